// Round 6
// baseline (624.545 us; speedup 1.0000x reference)
//
#include <hip/hip_runtime.h>
#include <hip/hip_bf16.h>
#include <cstdint>
#include <cstddef>

#define N 16384
#define DF 64
#define CHUNK 2048               // columns of A per L3-resident chunk (134 MB fp32)
#define NCHUNK (N / CHUNK)       // 8
#define KSUB 1024                // K-range per gemm slab
#define NSLAB (N / KSUB)         // 16

typedef __attribute__((ext_vector_type(8))) short short8;
typedef __attribute__((ext_vector_type(4))) float f32x4;

__device__ __forceinline__ unsigned short f2bf(float f) {
    union { float f; uint32_t u; } v; v.f = f;
    uint32_t u = v.u;
    uint32_t r = u + 0x7fffu + ((u >> 16) & 1u);  // RNE (data has no NaN/Inf)
    return (unsigned short)(r >> 16);
}

// ---------------- k1: partial column sums of one 2048-col chunk ----------------
// grid (2, 256): blockIdx.x = 1024-col strip, blockIdx.y = 64-row strip
__global__ __launch_bounds__(256) void colsum_chunk_kernel(const float* __restrict__ A,
                                                           float* __restrict__ partial,
                                                           int chunk) {
    int t = threadIdx.x;
    int cl = blockIdx.x * 1024 + t * 4;       // local col within chunk
    int c0 = chunk * CHUNK + cl;              // global col
    int r0 = blockIdx.y * 64;
    const float* p = A + (size_t)r0 * N + c0;
    float ax = 0.f, ay = 0.f, az = 0.f, aw = 0.f;
    #pragma unroll 8
    for (int r = 0; r < 64; ++r) {
        float4 v = *(const float4*)(p + (size_t)r * N);
        ax += v.x; ay += v.y; az += v.z; aw += v.w;
    }
    float4 o; o.x = ax; o.y = ay; o.z = az; o.w = aw;
    *(float4*)&partial[(size_t)blockIdx.y * CHUNK + cl] = o;
}

// ---------------- k2: reduce chunk partials -> d_inv slice + xs^T slice ----------------
// grid CHUNK/64 = 32 blocks
__global__ __launch_bounds__(256) void prep_chunk_kernel(const float* __restrict__ feat,
                                                         const float* __restrict__ partial,
                                                         float* __restrict__ d_inv,
                                                         unsigned short* __restrict__ xsT,
                                                         int chunk) {
    __shared__ float sums[4][64];
    __shared__ float tile[64][68];
    int t = threadIdx.x;
    int w = t >> 6, l = t & 63;
    int kl0 = blockIdx.x * 64;                // local k base within chunk
    int k0 = chunk * CHUNK + kl0;             // global k base
    // coalesced reduce: wave w sums partial rows [w*64, w*64+64)
    float s = 0.f;
    #pragma unroll 8
    for (int p = 0; p < 64; ++p)
        s += partial[(size_t)(w * 64 + p) * CHUNK + kl0 + l];
    sums[w][l] = s;
    __syncthreads();
    int r = t >> 2, q = t & 3;
    float dinv = 1.0f / (sums[0][r] + sums[1][r] + sums[2][r] + sums[3][r] + 1.0f);
    if (q == 0) d_inv[k0 + r] = dinv;

    int cq = q * 16;
    const float* fp = feat + (size_t)(k0 + r) * DF + cq;
    #pragma unroll
    for (int j = 0; j < 16; j += 4) {
        float4 v = *(const float4*)(fp + j);
        tile[r][cq + j + 0] = v.x * dinv;
        tile[r][cq + j + 1] = v.y * dinv;
        tile[r][cq + j + 2] = v.z * dinv;
        tile[r][cq + j + 3] = v.w * dinv;
    }
    __syncthreads();
    int f = t >> 2;          // feature 0..63
    int iq = (t & 3) * 16;   // 16 k's
    short8 b0, b1;
    #pragma unroll
    for (int j = 0; j < 8; ++j) b0[j] = (short)f2bf(tile[iq + j][f]);
    #pragma unroll
    for (int j = 0; j < 8; ++j) b1[j] = (short)f2bf(tile[iq + 8 + j][f]);
    unsigned short* dst = xsT + (size_t)f * N + k0 + iq;
    *(short8*)(dst) = b0;
    *(short8*)(dst + 8) = b1;
}

// ---------------- k3: slab[chunk*2+ksub] = A[:, krange] @ xs[krange]  (A re-read from L3) ----------------
#define BK 128
#define LDK 136              // padded LDS stride (elements)

__global__ __launch_bounds__(256, 8) void gemm_chunk_kernel(const float* __restrict__ A,
                                                            const unsigned short* __restrict__ xsT,
                                                            float* __restrict__ agg,
                                                            int chunk) {
    __shared__ __align__(16) unsigned short xtile[64 * LDK];
    int t = threadIdx.x;
    int mb = blockIdx.x >> 1;      // 0..255
    int ksub = blockIdx.x & 1;     // 0..1
    int m0 = mb * 64;
    int k0 = chunk * CHUNK + ksub * KSUB;
    int w = t >> 6;                // wave 0..3 -> rows [m0+16w, +16)
    int l = t & 63;
    int row = m0 + w * 16 + (l & 15);
    int kofs = (l >> 4) * 8;

    const float* arow = A + (size_t)row * N + k0 + kofs;

    f32x4 acc[4] = {};

    for (int kt = 0; kt < KSUB; kt += BK) {
        __syncthreads();  // previous tile fully consumed
        // stage xs^T tile: 64 features x BK k (1024 x 16B granules / 256 threads = 4 each)
        #pragma unroll
        for (int i = 0; i < 4; ++i) {
            int ch = t + i * 256;
            int f = ch >> 4;
            int ko = (ch & 15) * 8;
            *(short8*)&xtile[f * LDK + ko] =
                *(const short8*)&xsT[(size_t)f * N + k0 + kt + ko];
        }
        __syncthreads();
        #pragma unroll
        for (int kk = 0; kk < BK; kk += 32) {
            float4 a0 = *(const float4*)(arow + kt + kk);
            float4 a1 = *(const float4*)(arow + kt + kk + 4);
            short8 af;
            af[0] = (short)f2bf(a0.x); af[1] = (short)f2bf(a0.y);
            af[2] = (short)f2bf(a0.z); af[3] = (short)f2bf(a0.w);
            af[4] = (short)f2bf(a1.x); af[5] = (short)f2bf(a1.y);
            af[6] = (short)f2bf(a1.z); af[7] = (short)f2bf(a1.w);
            #pragma unroll
            for (int ct = 0; ct < 4; ++ct) {
                short8 bf = *(const short8*)&xtile[(ct * 16 + (l & 15)) * LDK + kk + kofs];
                acc[ct] = __builtin_amdgcn_mfma_f32_16x16x32_bf16(af, bf, acc[ct], 0, 0, 0);
            }
        }
    }
    // C/D layout: col = lane&15, row_in_tile = (lane>>4)*4 + reg
    float* slab = agg + (size_t)(chunk * 2 + ksub) * N * DF;
    int crow = m0 + w * 16 + (l >> 4) * 4;
    int ccol = l & 15;
    #pragma unroll
    for (int ct = 0; ct < 4; ++ct) {
        #pragma unroll
        for (int q = 0; q < 4; ++q)
            slab[(size_t)(crow + q) * DF + ct * 16 + ccol] = acc[ct][q];
    }
}

// ---------------- k4: out = relu(((sum slabs + f*dinv)*dinv) @ W + bias) ----------------
__global__ __launch_bounds__(256) void epilogue_kernel(const float* __restrict__ agg,
                                                       const float* __restrict__ feat,
                                                       const float* __restrict__ d_inv,
                                                       const float* __restrict__ W,
                                                       const float* __restrict__ bias,
                                                       float* __restrict__ out) {
    __shared__ float aggL[64][65];
    __shared__ float wL[64][64];
    int t = threadIdx.x;
    int i0 = blockIdx.x * 64;
    int r = t >> 2;
    int cq = (t & 3) * 16;
    {
        const float* wp = W + r * 64 + cq;
        #pragma unroll
        for (int j = 0; j < 16; j += 4) {
            float4 v = *(const float4*)(wp + j);
            wL[r][cq + j + 0] = v.x; wL[r][cq + j + 1] = v.y;
            wL[r][cq + j + 2] = v.z; wL[r][cq + j + 3] = v.w;
        }
    }
    float dinv = d_inv[i0 + r];
    const float* fp = feat + (size_t)(i0 + r) * DF + cq;
    size_t base = (size_t)(i0 + r) * DF + cq;
    #pragma unroll
    for (int j = 0; j < 16; j += 4) {
        float4 fv = *(const float4*)(fp + j);
        float sx = fv.x * dinv, sy = fv.y * dinv, sz = fv.z * dinv, sw = fv.w * dinv;
        #pragma unroll
        for (int sl = 0; sl < NSLAB; ++sl) {
            float4 a = *(const float4*)(agg + (size_t)sl * N * DF + base + j);
            sx += a.x; sy += a.y; sz += a.z; sw += a.w;
        }
        aggL[r][cq + j + 0] = sx * dinv;
        aggL[r][cq + j + 1] = sy * dinv;
        aggL[r][cq + j + 2] = sz * dinv;
        aggL[r][cq + j + 3] = sw * dinv;
    }
    __syncthreads();
    int k = t & 63;
    int rg = t >> 6;
    float bk = bias[k];
    for (int it = 0; it < 16; ++it) {
        int rr = rg * 16 + it;
        float acc = bk;
        #pragma unroll
        for (int c = 0; c < 64; ++c) acc += aggL[rr][c] * wL[c][k];
        out[(size_t)(i0 + rr) * DF + k] = fmaxf(acc, 0.0f);
    }
}

extern "C" void kernel_launch(void* const* d_in, const int* in_sizes, int n_in,
                              void* d_out, int out_size, void* d_ws, size_t ws_size,
                              hipStream_t stream) {
    const float* A    = (const float*)d_in[0];
    const float* feat = (const float*)d_in[1];
    const float* W    = (const float*)d_in[2];
    const float* bias = (const float*)d_in[3];
    float* out = (float*)d_out;

    float* ws = (float*)d_ws;
    float* partial = ws;                                   // 256*CHUNK floats (2 MB, reused per chunk)
    float* agg     = ws + (size_t)256 * CHUNK;             // NSLAB*N*64 floats (67 MB)
    float* dinv    = agg + (size_t)NSLAB * N * DF;         // N floats
    unsigned short* xsT = (unsigned short*)(dinv + N);     // 64*N bf16 (2.1 MB)

    for (int c = 0; c < NCHUNK; ++c) {
        colsum_chunk_kernel<<<dim3(2, 256), 256, 0, stream>>>(A, partial, c);
        prep_chunk_kernel<<<CHUNK / 64, 256, 0, stream>>>(feat, partial, dinv, xsT, c);
        gemm_chunk_kernel<<<512, 256, 0, stream>>>(A, xsT, agg, c);
    }
    epilogue_kernel<<<N / 64, 256, 0, stream>>>(agg, feat, dinv, W, bias, out);
}

// Round 7
// 460.295 us; speedup vs baseline: 1.3568x; 1.3568x over previous
//
#include <hip/hip_runtime.h>
#include <hip/hip_bf16.h>
#include <cstdint>
#include <cstddef>

#define N 16384
#define DF 64

typedef __attribute__((ext_vector_type(8))) short short8;
typedef __attribute__((ext_vector_type(4))) float f32x4;

__device__ __forceinline__ unsigned short f2bf(float f) {
    union { float f; uint32_t u; } v; v.f = f;
    uint32_t u = v.u;
    uint32_t r = u + 0x7fffu + ((u >> 16) & 1u);  // RNE (data has no NaN/Inf)
    return (unsigned short)(r >> 16);
}

// ---------------- k1: partial column sums of A (race-free) ----------------
// grid (16, 64): blockIdx.x = 1024-col chunk, blockIdx.y = 256-row chunk
#define PROWS 64
__global__ __launch_bounds__(256) void colsum_kernel(const float* __restrict__ A,
                                                     float* __restrict__ partial) {
    int t = threadIdx.x;
    int c0 = blockIdx.x * 1024 + t * 4;
    int r0 = blockIdx.y * 256;
    const float* p = A + (size_t)r0 * N + c0;
    float ax = 0.f, ay = 0.f, az = 0.f, aw = 0.f;
    #pragma unroll 8
    for (int r = 0; r < 256; ++r) {
        float4 v = *(const float4*)(p + (size_t)r * N);
        ax += v.x; ay += v.y; az += v.z; aw += v.w;
    }
    float4 o; o.x = ax; o.y = ay; o.z = az; o.w = aw;
    *(float4*)&partial[(size_t)blockIdx.y * N + c0] = o;
}

// ---------------- k2: reduce partials -> d_inv + xs^T (bf16, [64][N]) ----------------
__global__ __launch_bounds__(256) void prep_kernel(const float* __restrict__ feat,
                                                   const float* __restrict__ partial,
                                                   float* __restrict__ d_inv,
                                                   unsigned short* __restrict__ xsT) {
    __shared__ float tile[64][68];
    int t = threadIdx.x;
    int i0 = blockIdx.x * 64;
    int r = t >> 2;
    int q = t & 3;
    float s = 0.f;
    #pragma unroll
    for (int p = 0; p < 16; ++p)
        s += partial[(size_t)(q * 16 + p) * N + i0 + r];
    s += __shfl_xor(s, 1);
    s += __shfl_xor(s, 2);
    float dinv = 1.0f / (s + 1.0f);
    if (q == 0) d_inv[i0 + r] = dinv;

    int cq = q * 16;
    const float* fp = feat + (size_t)(i0 + r) * DF + cq;
    #pragma unroll
    for (int j = 0; j < 16; j += 4) {
        float4 v = *(const float4*)(fp + j);
        tile[r][cq + j + 0] = v.x * dinv;
        tile[r][cq + j + 1] = v.y * dinv;
        tile[r][cq + j + 2] = v.z * dinv;
        tile[r][cq + j + 3] = v.w * dinv;
    }
    __syncthreads();
    int c = t >> 2;
    int iq = (t & 3) * 16;
    short8 b0, b1;
    #pragma unroll
    for (int j = 0; j < 8; ++j) b0[j] = (short)f2bf(tile[iq + j][c]);
    #pragma unroll
    for (int j = 0; j < 8; ++j) b1[j] = (short)f2bf(tile[iq + 8 + j][c]);
    unsigned short* dst = xsT + (size_t)c * N + i0 + iq;
    *(short8*)(dst) = b0;
    *(short8*)(dst + 8) = b1;
}

// ---------------- k3: slab[ks] = A[:, chunk] @ xs[chunk] ----------------
// A staged through LDS with row-sequential 512B loads (DRAM-granularity fix).
#define KSPLIT 8
#define KCHUNK (N / KSPLIT)  // 2048
#define BK 128
#define LDK 136              // xs tile padded stride (elements)

__global__ __launch_bounds__(256, 4) void gemm_kernel(const float* __restrict__ A,
                                                      const unsigned short* __restrict__ xsT,
                                                      float* __restrict__ agg) {
    __shared__ __align__(16) unsigned short xtile[64 * LDK];  // 17.4 KB
    __shared__ __align__(16) unsigned short atile[64 * BK];   // 16 KB, XOR-swizzled
    int t = threadIdx.x;
    int bid = blockIdx.x;
    int mb = bid >> 3;       // 0..255
    int ks = bid & 7;        // 0..7
    int m0 = mb * 64;
    int k0 = ks * KCHUNK;
    int w = t >> 6;          // wave 0..3 -> rows [m0+16w, +16)
    int l = t & 63;

    // --- A staging mapping: thread t loads row srow, 32 consecutive k (128 B) ---
    int srow = t >> 2;       // 0..63
    int sq = t & 3;          // quarter of the 128-k tile
    const float* asrc = A + (size_t)(m0 + srow) * N + k0 + sq * 32;
    const int abyte_w = srow * (BK * 2) + sq * 64;   // pre-swizzle byte offset
    const int aswz_w = (srow & 7) << 4;

    // --- MFMA fragment read mapping ---
    int fr = l & 15;
    int fq = l >> 4;                       // 0..3
    int arow_l = w * 16 + fr;
    const int abyte_r = arow_l * (BK * 2) + fq * 16;
    const int aswz_r = (arow_l & 7) << 4;

    f32x4 acc[4] = {};

    for (int kt = 0; kt < KCHUNK; kt += BK) {
        __syncthreads();  // previous tile fully consumed
        // stage xs^T tile: 64 features x 128 k
        #pragma unroll
        for (int i = 0; i < 4; ++i) {
            int ch = t + i * 256;
            int f = ch >> 4;
            int ko = (ch & 15) * 8;
            *(short8*)&xtile[f * LDK + ko] =
                *(const short8*)&xsT[(size_t)f * N + k0 + kt + ko];
        }
        // stage A tile: 32 floats per thread, contiguous 128 B per thread (512 B/row)
        {
            float4 v0 = *(const float4*)(asrc + kt + 0);
            float4 v1 = *(const float4*)(asrc + kt + 4);
            float4 v2 = *(const float4*)(asrc + kt + 8);
            float4 v3 = *(const float4*)(asrc + kt + 12);
            float4 v4 = *(const float4*)(asrc + kt + 16);
            float4 v5 = *(const float4*)(asrc + kt + 20);
            float4 v6 = *(const float4*)(asrc + kt + 24);
            float4 v7 = *(const float4*)(asrc + kt + 28);
            short8 o0, o1, o2, o3;
            o0[0] = (short)f2bf(v0.x); o0[1] = (short)f2bf(v0.y);
            o0[2] = (short)f2bf(v0.z); o0[3] = (short)f2bf(v0.w);
            o0[4] = (short)f2bf(v1.x); o0[5] = (short)f2bf(v1.y);
            o0[6] = (short)f2bf(v1.z); o0[7] = (short)f2bf(v1.w);
            o1[0] = (short)f2bf(v2.x); o1[1] = (short)f2bf(v2.y);
            o1[2] = (short)f2bf(v2.z); o1[3] = (short)f2bf(v2.w);
            o1[4] = (short)f2bf(v3.x); o1[5] = (short)f2bf(v3.y);
            o1[6] = (short)f2bf(v3.z); o1[7] = (short)f2bf(v3.w);
            o2[0] = (short)f2bf(v4.x); o2[1] = (short)f2bf(v4.y);
            o2[2] = (short)f2bf(v4.z); o2[3] = (short)f2bf(v4.w);
            o2[4] = (short)f2bf(v5.x); o2[5] = (short)f2bf(v5.y);
            o2[6] = (short)f2bf(v5.z); o2[7] = (short)f2bf(v5.w);
            o3[0] = (short)f2bf(v6.x); o3[1] = (short)f2bf(v6.y);
            o3[2] = (short)f2bf(v6.z); o3[3] = (short)f2bf(v6.w);
            o3[4] = (short)f2bf(v7.x); o3[5] = (short)f2bf(v7.y);
            o3[6] = (short)f2bf(v7.z); o3[7] = (short)f2bf(v7.w);
            char* ab = (char*)atile;
            *(short8*)(ab + (((abyte_w + 0)  ^ aswz_w))) = o0;
            *(short8*)(ab + (((abyte_w + 16) ^ aswz_w))) = o1;
            *(short8*)(ab + (((abyte_w + 32) ^ aswz_w))) = o2;
            *(short8*)(ab + (((abyte_w + 48) ^ aswz_w))) = o3;
        }
        __syncthreads();
        const char* abr = (const char*)atile;
        #pragma unroll
        for (int kk = 0; kk < BK; kk += 32) {
            short8 af = *(const short8*)(abr + ((abyte_r + kk * 2) ^ aswz_r));
            #pragma unroll
            for (int ct = 0; ct < 4; ++ct) {
                short8 bf = *(const short8*)&xtile[(ct * 16 + fr) * LDK + kk + fq * 8];
                acc[ct] = __builtin_amdgcn_mfma_f32_16x16x32_bf16(af, bf, acc[ct], 0, 0, 0);
            }
        }
    }
    // C/D layout: col = lane&15, row_in_tile = (lane>>4)*4 + reg
    float* slab = agg + (size_t)ks * N * DF;
    int crow = m0 + w * 16 + (l >> 4) * 4;
    int ccol = l & 15;
    #pragma unroll
    for (int ct = 0; ct < 4; ++ct) {
        #pragma unroll
        for (int q = 0; q < 4; ++q)
            slab[(size_t)(crow + q) * DF + ct * 16 + ccol] = acc[ct][q];
    }
}

// ---------------- k4: out = relu(((sum slabs + f*dinv)*dinv) @ W + bias) ----------------
__global__ __launch_bounds__(256) void epilogue_kernel(const float* __restrict__ agg,
                                                       const float* __restrict__ feat,
                                                       const float* __restrict__ d_inv,
                                                       const float* __restrict__ W,
                                                       const float* __restrict__ bias,
                                                       float* __restrict__ out) {
    __shared__ float aggL[64][65];
    __shared__ float wL[64][64];
    int t = threadIdx.x;
    int i0 = blockIdx.x * 64;
    int r = t >> 2;
    int cq = (t & 3) * 16;
    {
        const float* wp = W + r * 64 + cq;
        #pragma unroll
        for (int j = 0; j < 16; j += 4) {
            float4 v = *(const float4*)(wp + j);
            wL[r][cq + j + 0] = v.x; wL[r][cq + j + 1] = v.y;
            wL[r][cq + j + 2] = v.z; wL[r][cq + j + 3] = v.w;
        }
    }
    float dinv = d_inv[i0 + r];
    const float* fp = feat + (size_t)(i0 + r) * DF + cq;
    size_t base = (size_t)(i0 + r) * DF + cq;
    #pragma unroll
    for (int j = 0; j < 16; j += 4) {
        float4 fv = *(const float4*)(fp + j);
        float sx = fv.x * dinv, sy = fv.y * dinv, sz = fv.z * dinv, sw = fv.w * dinv;
        #pragma unroll
        for (int sl = 0; sl < KSPLIT; ++sl) {
            float4 a = *(const float4*)(agg + (size_t)sl * N * DF + base + j);
            sx += a.x; sy += a.y; sz += a.z; sw += a.w;
        }
        aggL[r][cq + j + 0] = sx * dinv;
        aggL[r][cq + j + 1] = sy * dinv;
        aggL[r][cq + j + 2] = sz * dinv;
        aggL[r][cq + j + 3] = sw * dinv;
    }
    __syncthreads();
    int k = t & 63;
    int rg = t >> 6;
    float bk = bias[k];
    for (int it = 0; it < 16; ++it) {
        int rr = rg * 16 + it;
        float acc = bk;
        #pragma unroll
        for (int c = 0; c < 64; ++c) acc += aggL[rr][c] * wL[c][k];
        out[(size_t)(i0 + rr) * DF + k] = fmaxf(acc, 0.0f);
    }
}

extern "C" void kernel_launch(void* const* d_in, const int* in_sizes, int n_in,
                              void* d_out, int out_size, void* d_ws, size_t ws_size,
                              hipStream_t stream) {
    const float* A    = (const float*)d_in[0];
    const float* feat = (const float*)d_in[1];
    const float* W    = (const float*)d_in[2];
    const float* bias = (const float*)d_in[3];
    float* out = (float*)d_out;

    float* ws = (float*)d_ws;
    float* partial = ws;                                   // 64*N floats (4.2 MB)
    float* agg     = ws + (size_t)PROWS * N;               // KSPLIT*N*64 floats (33.6 MB)
    float* dinv    = agg + (size_t)KSPLIT * N * DF;        // N floats
    unsigned short* xsT = (unsigned short*)(dinv + N);     // 64*N bf16 (2.1 MB)

    colsum_kernel<<<dim3(16, 64), 256, 0, stream>>>(A, partial);
    prep_kernel<<<N / 64, 256, 0, stream>>>(feat, partial, dinv, xsT);
    gemm_kernel<<<(N / 64) * KSPLIT, 256, 0, stream>>>(A, xsT, agg);
    epilogue_kernel<<<N / 64, 256, 0, stream>>>(agg, feat, dinv, W, bias, out);
}

// Round 8
// 441.374 us; speedup vs baseline: 1.4150x; 1.0429x over previous
//
#include <hip/hip_runtime.h>
#include <hip/hip_bf16.h>
#include <cstdint>
#include <cstddef>

#define N 16384
#define DF 64

typedef __attribute__((ext_vector_type(8))) short short8;
typedef __attribute__((ext_vector_type(4))) float f32x4;

__device__ __forceinline__ unsigned short f2bf(float f) {
    union { float f; uint32_t u; } v; v.f = f;
    uint32_t u = v.u;
    uint32_t r = u + 0x7fffu + ((u >> 16) & 1u);  // RNE (data has no NaN/Inf)
    return (unsigned short)(r >> 16);
}

// ---------------- k1: partial column sums of A (race-free) ----------------
// grid (16, 64): blockIdx.x = 1024-col chunk, blockIdx.y = 256-row chunk
#define PROWS 64
__global__ __launch_bounds__(256) void colsum_kernel(const float* __restrict__ A,
                                                     float* __restrict__ partial) {
    int t = threadIdx.x;
    int c0 = blockIdx.x * 1024 + t * 4;
    int r0 = blockIdx.y * 256;
    const float* p = A + (size_t)r0 * N + c0;
    float ax = 0.f, ay = 0.f, az = 0.f, aw = 0.f;
    #pragma unroll 8
    for (int r = 0; r < 256; ++r) {
        float4 v = *(const float4*)(p + (size_t)r * N);
        ax += v.x; ay += v.y; az += v.z; aw += v.w;
    }
    float4 o; o.x = ax; o.y = ay; o.z = az; o.w = aw;
    *(float4*)&partial[(size_t)blockIdx.y * N + c0] = o;
}

// ---------------- k2: reduce partials -> d_inv + xs^T (bf16, [64][N]) ----------------
__global__ __launch_bounds__(256) void prep_kernel(const float* __restrict__ feat,
                                                   const float* __restrict__ partial,
                                                   float* __restrict__ d_inv,
                                                   unsigned short* __restrict__ xsT) {
    __shared__ float tile[64][68];
    int t = threadIdx.x;
    int i0 = blockIdx.x * 64;
    int r = t >> 2;
    int q = t & 3;
    float s = 0.f;
    #pragma unroll
    for (int p = 0; p < 16; ++p)
        s += partial[(size_t)(q * 16 + p) * N + i0 + r];
    s += __shfl_xor(s, 1);
    s += __shfl_xor(s, 2);
    float dinv = 1.0f / (s + 1.0f);
    if (q == 0) d_inv[i0 + r] = dinv;

    int cq = q * 16;
    const float* fp = feat + (size_t)(i0 + r) * DF + cq;
    #pragma unroll
    for (int j = 0; j < 16; j += 4) {
        float4 v = *(const float4*)(fp + j);
        tile[r][cq + j + 0] = v.x * dinv;
        tile[r][cq + j + 1] = v.y * dinv;
        tile[r][cq + j + 2] = v.z * dinv;
        tile[r][cq + j + 3] = v.w * dinv;
    }
    __syncthreads();
    int c = t >> 2;
    int iq = (t & 3) * 16;
    short8 b0, b1;
    #pragma unroll
    for (int j = 0; j < 8; ++j) b0[j] = (short)f2bf(tile[iq + j][c]);
    #pragma unroll
    for (int j = 0; j < 8; ++j) b1[j] = (short)f2bf(tile[iq + 8 + j][c]);
    unsigned short* dst = xsT + (size_t)c * N + i0 + iq;
    *(short8*)(dst) = b0;
    *(short8*)(dst + 8) = b1;
}

// ---------------- k3: slab[ks] = A[:, chunk] @ xs[chunk]  (bf16 MFMA) ----------------
// Single raw barrier per K-tile; loads stay in flight across barriers (T4-lite).
#define KSPLIT 8
#define KCHUNK (N / KSPLIT)  // 2048
#define BK 128
#define NT (KCHUNK / BK)     // 16
#define LDK 136              // padded LDS stride (elements)

__global__ __launch_bounds__(256, 4) void gemm_kernel(const float* __restrict__ A,
                                                      const unsigned short* __restrict__ xsT,
                                                      float* __restrict__ agg) {
    __shared__ __align__(16) unsigned short xtile[2][64 * LDK];  // 2 x 17.4 KB
    int t = threadIdx.x;
    int bid = blockIdx.x;
    int mb = bid >> 3;       // 0..255
    int ks = bid & 7;        // 0..7
    int m0 = mb * 64;
    int k0 = ks * KCHUNK;
    int w = t >> 6;          // wave 0..3 -> rows [m0+16w, +16)
    int l = t & 63;
    int fr = l & 15;
    int fq = l >> 4;
    int row = m0 + w * 16 + fr;
    const float* arow = A + (size_t)row * N + k0 + fq * 8;

    // B-stage thread mapping: thread handles chunks i=0..3 at feature f0+16i, k-offset ko
    int f0 = t >> 4;
    int ko = (t & 15) * 8;
    const unsigned short* bsrc = xsT + (size_t)f0 * N + k0 + ko;

    f32x4 acc[4] = {};
    short8 sreg[4];
    float4 ar[8];
    short8 abf[4];

    // ---- prologue: tile 0 ----
    #pragma unroll
    for (int i = 0; i < 4; ++i)
        sreg[i] = *(const short8*)(bsrc + (size_t)i * 16 * N);
    #pragma unroll
    for (int s = 0; s < 4; ++s) {
        ar[2 * s]     = *(const float4*)(arow + s * 32);
        ar[2 * s + 1] = *(const float4*)(arow + s * 32 + 4);
    }
    #pragma unroll
    for (int i = 0; i < 4; ++i)
        *(short8*)&xtile[0][(f0 + i * 16) * LDK + ko] = sreg[i];
    #pragma unroll
    for (int s = 0; s < 4; ++s) {
        short8 o;
        o[0] = (short)f2bf(ar[2*s].x);   o[1] = (short)f2bf(ar[2*s].y);
        o[2] = (short)f2bf(ar[2*s].z);   o[3] = (short)f2bf(ar[2*s].w);
        o[4] = (short)f2bf(ar[2*s+1].x); o[5] = (short)f2bf(ar[2*s+1].y);
        o[6] = (short)f2bf(ar[2*s+1].z); o[7] = (short)f2bf(ar[2*s+1].w);
        abf[s] = o;
    }
    asm volatile("s_waitcnt lgkmcnt(0)" ::: "memory");
    __builtin_amdgcn_s_barrier();

    int cur = 0;
    for (int tt = 0; tt < NT - 1; ++tt) {
        int kt2 = (tt + 1) * BK;
        // issue B-stage loads for tile t+1 (oldest in queue)
        #pragma unroll
        for (int i = 0; i < 4; ++i)
            sreg[i] = *(const short8*)(bsrc + (size_t)i * 16 * N + kt2);
        // issue A loads for tile t+1 (newer; stay in flight through ds_write's wait)
        #pragma unroll
        for (int s = 0; s < 4; ++s) {
            ar[2 * s]     = *(const float4*)(arow + kt2 + s * 32);
            ar[2 * s + 1] = *(const float4*)(arow + kt2 + s * 32 + 4);
        }
        // MFMA phase: consume xtile[cur] with pre-converted abf
        {
            const unsigned short* xr = &xtile[cur][0];
            #pragma unroll
            for (int s = 0; s < 4; ++s) {
                #pragma unroll
                for (int ct = 0; ct < 4; ++ct) {
                    short8 bf = *(const short8*)&xr[(ct * 16 + fr) * LDK + s * 32 + fq * 8];
                    acc[ct] = __builtin_amdgcn_mfma_f32_16x16x32_bf16(abf[s], bf, acc[ct], 0, 0, 0);
                }
            }
        }
        // ds_write staged B -> other buffer (waits only the 4 B-loads; A stays in flight)
        {
            unsigned short* xwd = &xtile[cur ^ 1][0];
            #pragma unroll
            for (int i = 0; i < 4; ++i)
                *(short8*)&xwd[(f0 + i * 16) * LDK + ko] = sreg[i];
        }
        // convert A late (its loads have had the whole MFMA phase to land)
        #pragma unroll
        for (int s = 0; s < 4; ++s) {
            short8 o;
            o[0] = (short)f2bf(ar[2*s].x);   o[1] = (short)f2bf(ar[2*s].y);
            o[2] = (short)f2bf(ar[2*s].z);   o[3] = (short)f2bf(ar[2*s].w);
            o[4] = (short)f2bf(ar[2*s+1].x); o[5] = (short)f2bf(ar[2*s+1].y);
            o[6] = (short)f2bf(ar[2*s+1].z); o[7] = (short)f2bf(ar[2*s+1].w);
            abf[s] = o;
        }
        asm volatile("s_waitcnt lgkmcnt(0)" ::: "memory");
        __builtin_amdgcn_s_barrier();
        cur ^= 1;
    }
    // ---- epilogue: consume last tile ----
    {
        const unsigned short* xr = &xtile[cur][0];
        #pragma unroll
        for (int s = 0; s < 4; ++s) {
            #pragma unroll
            for (int ct = 0; ct < 4; ++ct) {
                short8 bf = *(const short8*)&xr[(ct * 16 + fr) * LDK + s * 32 + fq * 8];
                acc[ct] = __builtin_amdgcn_mfma_f32_16x16x32_bf16(abf[s], bf, acc[ct], 0, 0, 0);
            }
        }
    }
    // C/D layout: col = lane&15, row_in_tile = (lane>>4)*4 + reg
    float* slab = agg + (size_t)ks * N * DF;
    int crow = m0 + w * 16 + (l >> 4) * 4;
    int ccol = l & 15;
    #pragma unroll
    for (int ct = 0; ct < 4; ++ct) {
        #pragma unroll
        for (int q = 0; q < 4; ++q)
            slab[(size_t)(crow + q) * DF + ct * 16 + ccol] = acc[ct][q];
    }
}

// ---------------- k4: out = relu(((sum slabs + f*dinv)*dinv) @ W + bias) ----------------
__global__ __launch_bounds__(256) void epilogue_kernel(const float* __restrict__ agg,
                                                       const float* __restrict__ feat,
                                                       const float* __restrict__ d_inv,
                                                       const float* __restrict__ W,
                                                       const float* __restrict__ bias,
                                                       float* __restrict__ out) {
    __shared__ float aggL[64][65];
    __shared__ float wL[64][64];
    int t = threadIdx.x;
    int i0 = blockIdx.x * 64;
    int r = t >> 2;
    int cq = (t & 3) * 16;
    {
        const float* wp = W + r * 64 + cq;
        #pragma unroll
        for (int j = 0; j < 16; j += 4) {
            float4 v = *(const float4*)(wp + j);
            wL[r][cq + j + 0] = v.x; wL[r][cq + j + 1] = v.y;
            wL[r][cq + j + 2] = v.z; wL[r][cq + j + 3] = v.w;
        }
    }
    float dinv = d_inv[i0 + r];
    const float* fp = feat + (size_t)(i0 + r) * DF + cq;
    size_t base = (size_t)(i0 + r) * DF + cq;
    #pragma unroll
    for (int j = 0; j < 16; j += 4) {
        float4 fv = *(const float4*)(fp + j);
        float sx = fv.x * dinv, sy = fv.y * dinv, sz = fv.z * dinv, sw = fv.w * dinv;
        #pragma unroll
        for (int sl = 0; sl < KSPLIT; ++sl) {
            float4 a = *(const float4*)(agg + (size_t)sl * N * DF + base + j);
            sx += a.x; sy += a.y; sz += a.z; sw += a.w;
        }
        aggL[r][cq + j + 0] = sx * dinv;
        aggL[r][cq + j + 1] = sy * dinv;
        aggL[r][cq + j + 2] = sz * dinv;
        aggL[r][cq + j + 3] = sw * dinv;
    }
    __syncthreads();
    int k = t & 63;
    int rg = t >> 6;
    float bk = bias[k];
    for (int it = 0; it < 16; ++it) {
        int rr = rg * 16 + it;
        float acc = bk;
        #pragma unroll
        for (int c = 0; c < 64; ++c) acc += aggL[rr][c] * wL[c][k];
        out[(size_t)(i0 + rr) * DF + k] = fmaxf(acc, 0.0f);
    }
}

extern "C" void kernel_launch(void* const* d_in, const int* in_sizes, int n_in,
                              void* d_out, int out_size, void* d_ws, size_t ws_size,
                              hipStream_t stream) {
    const float* A    = (const float*)d_in[0];
    const float* feat = (const float*)d_in[1];
    const float* W    = (const float*)d_in[2];
    const float* bias = (const float*)d_in[3];
    float* out = (float*)d_out;

    float* ws = (float*)d_ws;
    float* partial = ws;                                   // 64*N floats (4.2 MB)
    float* agg     = ws + (size_t)PROWS * N;               // KSPLIT*N*64 floats (33.6 MB)
    float* dinv    = agg + (size_t)KSPLIT * N * DF;        // N floats
    unsigned short* xsT = (unsigned short*)(dinv + N);     // 64*N bf16 (2.1 MB)

    colsum_kernel<<<dim3(16, 64), 256, 0, stream>>>(A, partial);
    prep_kernel<<<N / 64, 256, 0, stream>>>(feat, partial, dinv, xsT);
    gemm_kernel<<<(N / 64) * KSPLIT, 256, 0, stream>>>(A, xsT, agg);
    epilogue_kernel<<<N / 64, 256, 0, stream>>>(agg, feat, dinv, W, bias, out);
}